// Round 3
// baseline (388.258 us; speedup 1.0000x reference)
//
#include <hip/hip_runtime.h>
#include <math.h>

#define BB 16
#define CC 64
#define HH 224
#define WW 224
#define HWSZ (HH * WW)          // 50176
#define HW4 (HWSZ / 4)          // 12544
#define W4 (WW / 4)             // 56

typedef float f32x4 __attribute__((ext_vector_type(4)));

// ---------------- kernel A: channel mean+max reduce -------------------------
#define TA 256
#define NPIX (BB * HW4)         // 200704 float4 pixels
#define NBLKA (NPIX / TA)       // 784 blocks

__global__ __launch_bounds__(TA) void reduce_kernel(const float* __restrict__ x,
                                                    float* __restrict__ feat) {
    const int idx = blockIdx.x * TA + threadIdx.x;   // 0 .. NPIX-1
    const int b   = idx / HW4;
    const int p   = idx - b * HW4;
    const f32x4* xp = reinterpret_cast<const f32x4*>(x) + (size_t)b * (CC * HW4) + p;

    f32x4 s = {0.f, 0.f, 0.f, 0.f};
    f32x4 m = {-INFINITY, -INFINITY, -INFINITY, -INFINITY};
#pragma unroll 16
    for (int c = 0; c < CC; ++c) {
        f32x4 u = xp[(size_t)c * HW4];
        s += u;
        m[0] = fmaxf(m[0], u[0]); m[1] = fmaxf(m[1], u[1]);
        m[2] = fmaxf(m[2], u[2]); m[3] = fmaxf(m[3], u[3]);
    }
    f32x4* fav = reinterpret_cast<f32x4*>(feat);     // avg plane [16][HW]
    f32x4* fmx = fav + NPIX;                         // max plane [16][HW]
    fav[idx] = s * (1.0f / 64.0f);
    fmx[idx] = m;
}

// ---------------- kernel C: 7x7 conv + sigmoid -> gate (global) -------------
#define R 7
#define TILES (HH / R)          // 32
#define FR (R + 6)              // 13
#define FW 240
#define TC 256
#define NBLKC (BB * TILES)      // 512

__global__ __launch_bounds__(TC) void conv_kernel(const float* __restrict__ feat,
                                                  const float* __restrict__ cw,
                                                  const float* __restrict__ cb,
                                                  float* __restrict__ gate) {
    __shared__ float fa[FR * FW];
    __shared__ float fm[FR * FW];
    __shared__ float wt[98];

    const int blk = blockIdx.x;
    const int b   = blk >> 5;                  // TILES == 32
    const int tb  = blk & 31;
    const int h0  = tb * R;
    const int t   = threadIdx.x;

    for (int i = t; i < FR * FW; i += TC) { fa[i] = 0.f; fm[i] = 0.f; }
    if (t < 98) wt[t] = cw[t];
    __syncthreads();

    const f32x4* fav = reinterpret_cast<const f32x4*>(feat) + (size_t)b * HW4;
    const f32x4* fmx = fav + NPIX;
    for (int q = t; q < 2 * FR * W4; q += TC) {
        int plane = (q >= FR * W4);
        int p  = plane ? q - FR * W4 : q;
        int pr = p / W4;
        int pc = p - pr * W4;
        int gh = h0 - 3 + pr;
        if ((unsigned)gh >= (unsigned)HH) continue;   // stays zero (padding)
        f32x4 u = (plane ? fmx : fav)[gh * W4 + pc];
        float* dst = (plane ? fm : fa) + pr * FW + 3 + pc * 4;
        dst[0] = u[0]; dst[1] = u[1]; dst[2] = u[2]; dst[3] = u[3];
    }
    __syncthreads();

    const float bias = cb[0];
    float* gb = gate + (size_t)b * HWSZ + (size_t)h0 * WW;
    for (int p = t; p < R * WW; p += TC) {     // 1568 gate pixels
        int r = p / WW;
        int w = p - r * WW;
        float acc = bias;
#pragma unroll
        for (int kh = 0; kh < 7; ++kh) {
            int ro = (r + kh) * FW + w;
#pragma unroll
            for (int kw = 0; kw < 7; ++kw) {
                acc = fmaf(fa[ro + kw], wt[kh * 7 + kw], acc);
                acc = fmaf(fm[ro + kw], wt[49 + kh * 7 + kw], acc);
            }
        }
        gb[p] = 1.0f / (1.0f + expf(-acc));
    }
}

// ---------------- kernel M: out = x * gate (pure streamer) ------------------
#define TM 256
#define CSPL 4                  // channel-split: 4 groups of 16 channels
#define CPG (CC / CSPL)         // 16
#define CHUNKS (HW4 / TM)       // 49 pixel chunks per batch
#define NBLKM (BB * CSPL * CHUNKS)  // 3136 blocks (~12 blocks/CU)

__global__ __launch_bounds__(TM) void mul_kernel(const float* __restrict__ x,
                                                 const float* __restrict__ gate,
                                                 float* __restrict__ out) {
    const int blk   = blockIdx.x;
    const int chunk = blk % CHUNKS;
    const int cg    = (blk / CHUNKS) % CSPL;
    const int b     = blk / (CHUNKS * CSPL);
    const int p     = chunk * TM + threadIdx.x;      // float4 pixel in plane

    const f32x4 g = reinterpret_cast<const f32x4*>(gate)[(size_t)b * HW4 + p];

    const size_t base = ((size_t)b * CC + cg * CPG) * HW4 + p;
    const f32x4* xp = reinterpret_cast<const f32x4*>(x) + base;
    f32x4*       op = reinterpret_cast<f32x4*>(out) + base;
#pragma unroll
    for (int c = 0; c < CPG; ++c) {
        f32x4 v = xp[(size_t)c * HW4];
        v *= g;
        // write-once stream: keep the LLC free for x
        __builtin_nontemporal_store(v, op + (size_t)c * HW4);
    }
}

extern "C" void kernel_launch(void* const* d_in, const int* in_sizes, int n_in,
                              void* d_out, int out_size, void* d_ws, size_t ws_size,
                              hipStream_t stream) {
    const float* x  = (const float*)d_in[0];   // [16,64,224,224]
    const float* cw = (const float*)d_in[1];   // [1,2,7,7]
    const float* cb = (const float*)d_in[2];   // [1]
    float* out  = (float*)d_out;
    float* feat = (float*)d_ws;                          // 6.4 MB (avg+max planes)
    float* gate = feat + (size_t)2 * BB * HWSZ;          // 3.2 MB

    reduce_kernel<<<NBLKA, TA, 0, stream>>>(x, feat);
    conv_kernel<<<NBLKC, TC, 0, stream>>>(feat, cw, cb, gate);
    mul_kernel<<<NBLKM, TM, 0, stream>>>(x, gate, out);
}